// Round 12
// baseline (98.212 us; speedup 1.0000x reference)
//
#include <hip/hip_runtime.h>

// Fused LSTM: B=4096, T=200, F=64, H=16, O=1.
// R11 + ONE-LINE FIX: epilogue was missing "+ bout[0]" (R10/R11 failures
// were exactly this: |bout|*sigmoid-slope ~= 0.05 = observed absmax).
//
// 256 blocks x 4 symmetric waves; 16 batches/block; r-split consumer:
// the 16x16x16 MFMA D-tile gives each lane rows r=0..3 -- wave w keeps only
// row r=w, cutting per-wave transcendental issue 4x. Every wave redundantly
// computes all 4 recurrence MFMAs + the next step's input projection
// (off-chain, double-buffered Ct; x re-reads hit L1/L2). h exchanged per
// step via 1.3KB double-buffered LDS (layout == next step's B-fragment)
// with ONE lgkmcnt-only barrier per step (x loads float across barriers).

#define Bsz 4096
#define Tn  200
#define Fn  64
#define Hn  16

#define CM1 -1.4426950408889634f   // -log2(e)
#define CM2 -2.8853900817779268f   // -2*log2(e)

typedef _Float16 half8 __attribute__((ext_vector_type(8)));
typedef _Float16 half4 __attribute__((ext_vector_type(4)));
typedef float    f32x4 __attribute__((ext_vector_type(4)));

__device__ __forceinline__ half8 to_half8s(const float4& a, const float4& b) {
    half8 h;
    h[0] = (_Float16)a.x; h[1] = (_Float16)a.y; h[2] = (_Float16)a.z; h[3] = (_Float16)a.w;
    h[4] = (_Float16)b.x; h[5] = (_Float16)b.y; h[6] = (_Float16)b.z; h[7] = (_Float16)b.w;
    return h;
}

// LDS-visibility-only barrier: does NOT drain vmcnt, so register-targeted
// global loads stay in flight across it.
__device__ __forceinline__ void lds_barrier() {
    __builtin_amdgcn_sched_barrier(0);
    asm volatile("s_waitcnt lgkmcnt(0)" ::: "memory");
    __builtin_amdgcn_s_barrier();
    __builtin_amdgcn_sched_barrier(0);
}

template <int R>
__device__ __forceinline__ void lstm_step(
    int t, float4 (&slot)[4], f32x4 (&Ccur)[4], f32x4 (&Cnext)[4],
    const half8 (&WihF)[4][2], const half4 (&WhhF)[4], const f32x4 (&biasC)[4],
    const float* __restrict__ xl,
    const _Float16* hread, _Float16* hwrite,
    int l15, int lhi, float& cst)
{
    // ---- serial chain: read h_t (B-frag layout: col=l15 batch, k=lhi*4+j unit)
    half4 hv = *reinterpret_cast<const half4*>(hread + l15 * 20 + lhi * 4);
    f32x4 pre0 = __builtin_amdgcn_mfma_f32_16x16x16f16(WhhF[0], hv, Ccur[0], 0, 0, 0);
    f32x4 pre1 = __builtin_amdgcn_mfma_f32_16x16x16f16(WhhF[1], hv, Ccur[1], 0, 0, 0);
    f32x4 pre2 = __builtin_amdgcn_mfma_f32_16x16x16f16(WhhF[2], hv, Ccur[2], 0, 0, 0);
    f32x4 pre3 = __builtin_amdgcn_mfma_f32_16x16x16f16(WhhF[3], hv, Ccur[3], 0, 0, 0);

    // ---- off-chain: input projection for step t+1; reload slot with x(t+5)
    half8 f0 = to_half8s(slot[0], slot[1]);
    half8 f1 = to_half8s(slot[2], slot[3]);
#pragma unroll
    for (int m = 0; m < 4; ++m) {
        Cnext[m] = __builtin_amdgcn_mfma_f32_16x16x32_f16(WihF[m][0], f0, biasC[m], 0, 0, 0);
        Cnext[m] = __builtin_amdgcn_mfma_f32_16x16x32_f16(WihF[m][1], f1, Cnext[m], 0, 0, 0);
    }
    {
        const int tl = (t + 5 > Tn - 1) ? Tn - 1 : t + 5;
        const float* xp = xl + (size_t)tl * Fn;
        slot[0] = *reinterpret_cast<const float4*>(xp);
        slot[1] = *reinterpret_cast<const float4*>(xp + 4);
        slot[2] = *reinterpret_cast<const float4*>(xp + 32);
        slot[3] = *reinterpret_cast<const float4*>(xp + 36);
    }

    // ---- activations, row R only (R9's verified formula: f32 cm multiply)
    float ig = __builtin_amdgcn_rcpf(1.0f + __builtin_amdgcn_exp2f(pre0[R] * CM1));
    float fg = __builtin_amdgcn_rcpf(1.0f + __builtin_amdgcn_exp2f(pre1[R] * CM1));
    float gg = fmaf(2.0f, __builtin_amdgcn_rcpf(
        1.0f + __builtin_amdgcn_exp2f(pre2[R] * CM2)), -1.0f);
    float og = __builtin_amdgcn_rcpf(1.0f + __builtin_amdgcn_exp2f(pre3[R] * CM1));
    cst = fmaf(fg, cst, ig * gg);
    float th = fmaf(2.0f, __builtin_amdgcn_rcpf(
        1.0f + __builtin_amdgcn_exp2f(cst * CM2)), -1.0f);
    hwrite[l15 * 20 + lhi * 4 + R] = (_Float16)(og * th);

    lds_barrier();
}

template <int R>
__device__ __forceinline__ void run_wave(
    float4 (&ring)[4][4], f32x4 (&CtA)[4], f32x4 (&CtB)[4],
    const half8 (&WihF)[4][2], const half4 (&WhhF)[4], const f32x4 (&biasC)[4],
    const float* __restrict__ xl, _Float16* h0, _Float16* h1,
    int l15, int lhi, float& cst)
{
#pragma unroll 1
    for (int t = 0; t < Tn; t += 4) {
        lstm_step<R>(t,     ring[1], CtA, CtB, WihF, WhhF, biasC, xl, h0, h1, l15, lhi, cst);
        lstm_step<R>(t + 1, ring[2], CtB, CtA, WihF, WhhF, biasC, xl, h1, h0, l15, lhi, cst);
        lstm_step<R>(t + 2, ring[3], CtA, CtB, WihF, WhhF, biasC, xl, h0, h1, l15, lhi, cst);
        lstm_step<R>(t + 3, ring[0], CtB, CtA, WihF, WhhF, biasC, xl, h1, h0, l15, lhi, cst);
    }
}

__global__ __launch_bounds__(256, 1) void lstm_fused(
    const float* __restrict__ x,     // [B, T, F]
    const float* __restrict__ Wih,   // [64, 64]
    const float* __restrict__ Whh,   // [64, 16]
    const float* __restrict__ bih,   // [64]
    const float* __restrict__ bhh,   // [64]
    const float* __restrict__ Wout,  // [1, 16]
    const float* __restrict__ bout,  // [1]
    float* __restrict__ out)         // [B, 1]
{
    const int lane = threadIdx.x & 63;
    const int wave = threadIdx.x >> 6;
    const int l15  = lane & 15;
    const int lhi  = lane >> 4;
    const int b    = (int)blockIdx.x * 16 + l15;

    // h exchange: [parity][batch][unit, padded to 20 f16 for bank spread]
    __shared__ __align__(16) _Float16 hbuf[2][16][20];
    if (threadIdx.x < 40)
        reinterpret_cast<float4*>(&hbuf[0][0][0])[threadIdx.x] = float4{0.f, 0.f, 0.f, 0.f};

    // ---- unscaled f16 weights (R9-verified numerics)
    half8 WihF[4][2];
    half4 WhhF[4];
    f32x4 biasC[4];
#pragma unroll
    for (int m = 0; m < 4; ++m) {
#pragma unroll
        for (int kh = 0; kh < 2; ++kh) {
            const float* wr = Wih + (m * 16 + l15) * Fn + kh * 32 + lhi * 8;
            float4 w0 = *reinterpret_cast<const float4*>(wr);
            float4 w1 = *reinterpret_cast<const float4*>(wr + 4);
            WihF[m][kh] = to_half8s(w0, w1);
        }
        float4 wh = *reinterpret_cast<const float4*>(Whh + (m * 16 + l15) * Hn + lhi * 4);
        WhhF[m][0] = (_Float16)wh.x; WhhF[m][1] = (_Float16)wh.y;
        WhhF[m][2] = (_Float16)wh.z; WhhF[m][3] = (_Float16)wh.w;
        float4 v0 = *reinterpret_cast<const float4*>(bih + m * 16 + lhi * 4);
        float4 v1 = *reinterpret_cast<const float4*>(bhh + m * 16 + lhi * 4);
        biasC[m][0] = v0.x + v1.x; biasC[m][1] = v0.y + v1.y;
        biasC[m][2] = v0.z + v1.z; biasC[m][3] = v0.w + v1.w;
    }

    // ---- x ring: slots 0..3 hold x(0..3); B-frag: col=l15 batch, k=feat
    const float* xl = x + (size_t)b * (Tn * Fn) + lhi * 8;
    float4 ring[4][4];
#pragma unroll
    for (int s2 = 0; s2 < 4; ++s2) {
        const float* xp = xl + s2 * Fn;
        ring[s2][0] = *reinterpret_cast<const float4*>(xp);
        ring[s2][1] = *reinterpret_cast<const float4*>(xp + 4);
        ring[s2][2] = *reinterpret_cast<const float4*>(xp + 32);
        ring[s2][3] = *reinterpret_cast<const float4*>(xp + 36);
    }

    // CtA = proj(x(0)); then ring[0] <- x(4)
    f32x4 CtA[4], CtB[4];
    {
        half8 f0 = to_half8s(ring[0][0], ring[0][1]);
        half8 f1 = to_half8s(ring[0][2], ring[0][3]);
#pragma unroll
        for (int m = 0; m < 4; ++m) {
            CtA[m] = __builtin_amdgcn_mfma_f32_16x16x32_f16(WihF[m][0], f0, biasC[m], 0, 0, 0);
            CtA[m] = __builtin_amdgcn_mfma_f32_16x16x32_f16(WihF[m][1], f1, CtA[m], 0, 0, 0);
        }
        const float* xp = xl + 4 * Fn;
        ring[0][0] = *reinterpret_cast<const float4*>(xp);
        ring[0][1] = *reinterpret_cast<const float4*>(xp + 4);
        ring[0][2] = *reinterpret_cast<const float4*>(xp + 32);
        ring[0][3] = *reinterpret_cast<const float4*>(xp + 36);
    }

    __syncthreads();

    float cst = 0.0f;
    _Float16* h0 = &hbuf[0][0][0];
    _Float16* h1 = &hbuf[1][0][0];
    switch (wave) {
        case 0:  run_wave<0>(ring, CtA, CtB, WihF, WhhF, biasC, xl, h0, h1, l15, lhi, cst); break;
        case 1:  run_wave<1>(ring, CtA, CtB, WihF, WhhF, biasC, xl, h0, h1, l15, lhi, cst); break;
        case 2:  run_wave<2>(ring, CtA, CtB, WihF, WhhF, biasC, xl, h0, h1, l15, lhi, cst); break;
        default: run_wave<3>(ring, CtA, CtB, WihF, WhhF, biasC, xl, h0, h1, l15, lhi, cst); break;
    }

    // ---- epilogue: final h is in hbuf[0]; Linear(16->1) + sigmoid
    if (wave == 0) {
        const half4 hf = *reinterpret_cast<const half4*>(&hbuf[0][l15][lhi * 4]);
        float4 wo = *reinterpret_cast<const float4*>(Wout + lhi * 4);
        float po = (float)hf[0] * wo.x;
        po = fmaf((float)hf[1], wo.y, po);
        po = fmaf((float)hf[2], wo.z, po);
        po = fmaf((float)hf[3], wo.w, po);
        po += __shfl_xor(po, 16);
        po += __shfl_xor(po, 32);
        if (lhi == 0)
            out[b] = __builtin_amdgcn_rcpf(
                1.0f + __builtin_amdgcn_exp2f((po + bout[0]) * CM1));
    }
}

extern "C" void kernel_launch(void* const* d_in, const int* in_sizes, int n_in,
                              void* d_out, int out_size, void* d_ws, size_t ws_size,
                              hipStream_t stream) {
    const float* x    = (const float*)d_in[0];
    const float* Wih  = (const float*)d_in[1];
    const float* Whh  = (const float*)d_in[2];
    const float* bih  = (const float*)d_in[3];
    const float* bhh  = (const float*)d_in[4];
    const float* Wout = (const float*)d_in[5];
    const float* bout = (const float*)d_in[6];
    float* out = (float*)d_out;

    lstm_fused<<<dim3(Bsz / 16), dim3(256), 0, stream>>>(
        x, Wih, Whh, bih, bhh, Wout, bout, out);
}

// Round 13
// 78.287 us; speedup vs baseline: 1.2545x; 1.2545x over previous
//
#include <hip/hip_runtime.h>

// Fused LSTM: B=4096, T=200, F=64, H=16, O=1.
// R9 structure (best: 72.7us) + spine surgery ONLY:
//  - tanh(c) via Pade(5,4) x(945+105u+u^2)/(945+420u+15u^2), u=x^2, + clamp:
//    ONE rcp on the serial chain instead of exp2+rcp (err<=1.7e-3 @|x|~3.8;
//    ratio>=1 for |x|>=4 so clamp covers all large |c|).
//  - f-gate MFMA first (its sigmoid is the spine head).
//  - h pack via 2x v_cvt_pkrtz (was 4 scalar cvt).
// Everything else identical to R9: producer/consumer, 3 waves/block
// (1 consumer + 2 producers), 16 batches/block, gx via MFMA into 3-deep
// LDS ring, lgkmcnt-only chunk barriers, 1-MFMA f16 recurrence.

#define Bsz 4096
#define Tn  200
#define Fn  64
#define Hn  16
#define CS  8     // steps per chunk
#define NCH 25    // chunks (25*8 = 200)

#define CM1 -1.4426950408889634f   // -log2(e)
#define CM2 -2.8853900817779268f   // -2*log2(e)

typedef _Float16 half8 __attribute__((ext_vector_type(8)));
typedef _Float16 half4 __attribute__((ext_vector_type(4)));
typedef float    f32x4 __attribute__((ext_vector_type(4)));

__device__ __forceinline__ half8 to_half8(const float4& a, const float4& b) {
    half8 h;
    h[0] = (_Float16)a.x; h[1] = (_Float16)a.y; h[2] = (_Float16)a.z; h[3] = (_Float16)a.w;
    h[4] = (_Float16)b.x; h[5] = (_Float16)b.y; h[6] = (_Float16)b.z; h[7] = (_Float16)b.w;
    return h;
}

__device__ __forceinline__ float sigm(float z) {
    return __builtin_amdgcn_rcpf(1.0f + __builtin_amdgcn_exp2f(z * CM1));
}
__device__ __forceinline__ float tanhe(float z) {   // exp2-based (off-spine, g-gate)
    return fmaf(2.0f, __builtin_amdgcn_rcpf(
        1.0f + __builtin_amdgcn_exp2f(z * CM2)), -1.0f);
}
// Pade(5,4) tanh with clamp -- 1 rcp, no exp2 (spine use, tanh(c))
__device__ __forceinline__ float tanhp(float x) {
    float u   = x * x;
    float num = x * fmaf(u, u + 105.0f, 945.0f);            // x(945+105u+u^2)
    float den = fmaf(u, fmaf(15.0f, u, 420.0f), 945.0f);    // 945+420u+15u^2
    float th  = num * __builtin_amdgcn_rcpf(den);
    return fminf(fmaxf(th, -1.0f), 1.0f);
}

// LDS-visibility-only barrier: does NOT drain vmcnt (register-targeted
// global loads stay in flight across it).
__device__ __forceinline__ void lds_barrier() {
    __builtin_amdgcn_sched_barrier(0);
    asm volatile("s_waitcnt lgkmcnt(0)" ::: "memory");
    __builtin_amdgcn_s_barrier();
    __builtin_amdgcn_sched_barrier(0);
}

__global__ __launch_bounds__(192, 1) void lstm_fused(
    const float* __restrict__ x,     // [B, T, F]
    const float* __restrict__ Wih,   // [64, 64]
    const float* __restrict__ Whh,   // [64, 16]
    const float* __restrict__ bih,   // [64]
    const float* __restrict__ bhh,   // [64]
    const float* __restrict__ Wout,  // [1, 16]
    const float* __restrict__ bout,  // [1]
    float* __restrict__ out)         // [B, 1]
{
    const int lane = threadIdx.x & 63;
    const int wave = threadIdx.x >> 6;   // 0 = consumer, 1/2 = producers
    const int l15  = lane & 15;
    const int lhi  = lane >> 4;
    const int b    = (int)blockIdx.x * 16 + l15;   // per-lane batch

    // gx ring: [buf][step][gate-tile m][lane] f32x4 = 3*8*4*64*16 B = 96 KiB
    __shared__ f32x4 gxbuf[3][CS][4][64];

    // ================= producer-side state =================
    half8 WihF[4][2];
    f32x4 biasC[4];
    float4 xr[4][4];                       // 4 staged steps per producer
    const int pofs = (wave - 1) * 4;       // this producer's step offset
    const float* xl = x + (size_t)b * (Tn * Fn) + lhi * 8;

    if (wave >= 1) {
#pragma unroll
        for (int m = 0; m < 4; ++m)
#pragma unroll
            for (int kh = 0; kh < 2; ++kh) {
                const float* wr = Wih + (m * 16 + l15) * Fn + kh * 32 + lhi * 8;
                float4 w0 = *reinterpret_cast<const float4*>(wr);
                float4 w1 = *reinterpret_cast<const float4*>(wr + 4);
                WihF[m][kh] = to_half8(w0, w1);
            }
#pragma unroll
        for (int m = 0; m < 4; ++m) {
            float4 v0 = *reinterpret_cast<const float4*>(bih + m * 16 + lhi * 4);
            float4 v1 = *reinterpret_cast<const float4*>(bhh + m * 16 + lhi * 4);
            biasC[m][0] = v0.x + v1.x; biasC[m][1] = v0.y + v1.y;
            biasC[m][2] = v0.z + v1.z; biasC[m][3] = v0.w + v1.w;
        }
        // prologue: stage my 4 steps of chunk 0
#pragma unroll
        for (int s = 0; s < 4; ++s) {
            const float* xp = xl + (pofs + s) * Fn;
            xr[s][0] = *reinterpret_cast<const float4*>(xp);
            xr[s][1] = *reinterpret_cast<const float4*>(xp + 4);
            xr[s][2] = *reinterpret_cast<const float4*>(xp + 32);
            xr[s][3] = *reinterpret_cast<const float4*>(xp + 36);
        }
    }

    // ================= consumer-side state =================
    half4 WhhF[4];
#pragma unroll
    for (int m = 0; m < 4; ++m) {
        float4 w = *reinterpret_cast<const float4*>(Whh + (m * 16 + l15) * Hn + lhi * 4);
        WhhF[m][0] = (_Float16)w.x; WhhF[m][1] = (_Float16)w.y;
        WhhF[m][2] = (_Float16)w.z; WhhF[m][3] = (_Float16)w.w;
    }

    f32x4 cst = { 0.0f, 0.0f, 0.0f, 0.0f };
    half4 hHi = { 0, 0, 0, 0 };
    float hcur[4] = { 0.0f, 0.0f, 0.0f, 0.0f };

    // one recurrence + cell step consuming gx tiles g[0..3]
    auto recur = [&](f32x4 (&g)[4]) {
        // f-gate first: it heads the serial spine (f -> c -> tanh -> h)
        f32x4 pre1 = __builtin_amdgcn_mfma_f32_16x16x16f16(WhhF[1], hHi, g[1], 0, 0, 0);
        f32x4 pre0 = __builtin_amdgcn_mfma_f32_16x16x16f16(WhhF[0], hHi, g[0], 0, 0, 0);
        f32x4 pre2 = __builtin_amdgcn_mfma_f32_16x16x16f16(WhhF[2], hHi, g[2], 0, 0, 0);
        f32x4 pre3 = __builtin_amdgcn_mfma_f32_16x16x16f16(WhhF[3], hHi, g[3], 0, 0, 0);
#pragma unroll
        for (int r = 0; r < 4; ++r) {
            float fg = sigm(pre1[r]);
            float ig = sigm(pre0[r]);
            float gg = tanhe(pre2[r]);
            float og = sigm(pre3[r]);
            cst[r]  = fmaf(fg, cst[r], ig * gg);
            hcur[r] = og * tanhp(cst[r]);
        }
        auto p01 = __builtin_amdgcn_cvt_pkrtz(hcur[0], hcur[1]);
        auto p23 = __builtin_amdgcn_cvt_pkrtz(hcur[2], hcur[3]);
        hHi[0] = (_Float16)p01[0]; hHi[1] = (_Float16)p01[1];
        hHi[2] = (_Float16)p23[0]; hHi[3] = (_Float16)p23[1];
    };

    // ================= pipelined main loop =================
#pragma unroll 1
    for (int i = 0; i < NCH + 2; ++i) {
        lds_barrier();
        if (wave >= 1) {
            // ---- producers: compute my 4 steps of chunk i; reload xr[s]
            //      (chunk i+1) right after consuming it
            if (i < NCH) {
                const int bi  = i % 3;
                const int cnx = (i + 1 < NCH) ? i + 1 : NCH - 1;   // clamp
#pragma unroll
                for (int s = 0; s < 4; ++s) {
                    half8 f0 = to_half8(xr[s][0], xr[s][1]);
                    half8 f1 = to_half8(xr[s][2], xr[s][3]);
                    const float* xp = xl + (size_t)(cnx * CS + pofs + s) * Fn;
                    xr[s][0] = *reinterpret_cast<const float4*>(xp);
                    xr[s][1] = *reinterpret_cast<const float4*>(xp + 4);
                    xr[s][2] = *reinterpret_cast<const float4*>(xp + 32);
                    xr[s][3] = *reinterpret_cast<const float4*>(xp + 36);
#pragma unroll
                    for (int m = 0; m < 4; ++m) {
                        f32x4 acc = __builtin_amdgcn_mfma_f32_16x16x32_f16(
                            WihF[m][0], f0, biasC[m], 0, 0, 0);
                        acc = __builtin_amdgcn_mfma_f32_16x16x32_f16(
                            WihF[m][1], f1, acc, 0, 0, 0);
                        gxbuf[bi][pofs + s][m][lane] = acc;
                    }
                }
            }
        } else {
            // ---- consumer: recurrence over chunk i-2
            if (i >= 2) {
                const int bi = (i - 2) % 3;
                f32x4 gA[4], gB[4];
#pragma unroll
                for (int m = 0; m < 4; ++m) gA[m] = gxbuf[bi][0][m][lane];
#pragma unroll
                for (int m = 0; m < 4; ++m) gB[m] = gxbuf[bi][1][m][lane];
                recur(gA);
#pragma unroll
                for (int m = 0; m < 4; ++m) gA[m] = gxbuf[bi][2][m][lane];
                recur(gB);
#pragma unroll
                for (int m = 0; m < 4; ++m) gB[m] = gxbuf[bi][3][m][lane];
                recur(gA);
#pragma unroll
                for (int m = 0; m < 4; ++m) gA[m] = gxbuf[bi][4][m][lane];
                recur(gB);
#pragma unroll
                for (int m = 0; m < 4; ++m) gB[m] = gxbuf[bi][5][m][lane];
                recur(gA);
#pragma unroll
                for (int m = 0; m < 4; ++m) gA[m] = gxbuf[bi][6][m][lane];
                recur(gB);
#pragma unroll
                for (int m = 0; m < 4; ++m) gB[m] = gxbuf[bi][7][m][lane];
                recur(gA);
                recur(gB);
            }
        }
    }

    // ================= epilogue: Linear(16->1) + sigmoid =================
    if (wave == 0) {
        float4 wo = *reinterpret_cast<const float4*>(Wout + lhi * 4);
        float po = hcur[0] * wo.x;
        po = fmaf(hcur[1], wo.y, po);
        po = fmaf(hcur[2], wo.z, po);
        po = fmaf(hcur[3], wo.w, po);
        po += __shfl_xor(po, 16);
        po += __shfl_xor(po, 32);
        if (lhi == 0)
            out[b] = sigm(po + bout[0]);
    }
}

extern "C" void kernel_launch(void* const* d_in, const int* in_sizes, int n_in,
                              void* d_out, int out_size, void* d_ws, size_t ws_size,
                              hipStream_t stream) {
    const float* x    = (const float*)d_in[0];
    const float* Wih  = (const float*)d_in[1];
    const float* Whh  = (const float*)d_in[2];
    const float* bih  = (const float*)d_in[3];
    const float* bhh  = (const float*)d_in[4];
    const float* Wout = (const float*)d_in[5];
    const float* bout = (const float*)d_in[6];
    float* out = (float*)d_out;

    lstm_fused<<<dim3(Bsz / 16), dim3(192), 0, stream>>>(
        x, Wih, Whh, bih, bhh, Wout, bout, out);
}

// Round 14
// 73.988 us; speedup vs baseline: 1.3274x; 1.0581x over previous
//
#include <hip/hip_runtime.h>

// Fused LSTM: B=4096, T=200, F=64, H=16, O=1.
// R9 structure with the chunk barriers replaced by a bounded-buffer FLAG
// handshake (no s_barrier in the main loop): consumer free-runs; producers
// spin (s_sleep) on consumer progress. Ring-3 depth >= lag 2 -> deadlock-free.
//  - prod_done[p] = chunks completed by producer p (release after ds_writes)
//  - cons_done    = chunks consumed (release after last read of the chunk)
// Plus R13's two non-negative micro-wins: f-gate MFMA first, cvt_pkrtz pack.
//
// Producer/consumer, 3 waves/block (1 consumer + 2 producers), 16 batches/blk.
//   pre^T(64x16) = Wih(64x64) @ x_t^T + Whh(64x16) @ h^T + bias
// Producers: input projection on MFMA (bias in C), 4 steps each per 8-step
// chunk, register-staged x reloaded per-step during compute, gx f32x4 tiles
// -> 3-deep LDS ring. Consumer: per step one mfma_16x16x16f16(WhhF,h,gx)
// + lane-local cell update; D-tile rows == next B-frag k-slots -> zero
// cross-lane ops on the serial chain.

#define Bsz 4096
#define Tn  200
#define Fn  64
#define Hn  16
#define CS  8     // steps per chunk
#define NCH 25    // chunks (25*8 = 200)

#define CM1 -1.4426950408889634f   // -log2(e)
#define CM2 -2.8853900817779268f   // -2*log2(e)

typedef _Float16 half8 __attribute__((ext_vector_type(8)));
typedef _Float16 half4 __attribute__((ext_vector_type(4)));
typedef float    f32x4 __attribute__((ext_vector_type(4)));

__device__ __forceinline__ half8 to_half8(const float4& a, const float4& b) {
    half8 h;
    h[0] = (_Float16)a.x; h[1] = (_Float16)a.y; h[2] = (_Float16)a.z; h[3] = (_Float16)a.w;
    h[4] = (_Float16)b.x; h[5] = (_Float16)b.y; h[6] = (_Float16)b.z; h[7] = (_Float16)b.w;
    return h;
}

__device__ __forceinline__ float sigm(float z) {
    return __builtin_amdgcn_rcpf(1.0f + __builtin_amdgcn_exp2f(z * CM1));
}
__device__ __forceinline__ float tanhe(float z) {
    return fmaf(2.0f, __builtin_amdgcn_rcpf(
        1.0f + __builtin_amdgcn_exp2f(z * CM2)), -1.0f);
}

__global__ __launch_bounds__(192, 1) void lstm_fused(
    const float* __restrict__ x,     // [B, T, F]
    const float* __restrict__ Wih,   // [64, 64]
    const float* __restrict__ Whh,   // [64, 16]
    const float* __restrict__ bih,   // [64]
    const float* __restrict__ bhh,   // [64]
    const float* __restrict__ Wout,  // [1, 16]
    const float* __restrict__ bout,  // [1]
    float* __restrict__ out)         // [B, 1]
{
    const int lane = threadIdx.x & 63;
    const int wave = threadIdx.x >> 6;   // 0 = consumer, 1/2 = producers
    const int l15  = lane & 15;
    const int lhi  = lane >> 4;
    const int b    = (int)blockIdx.x * 16 + l15;   // per-lane batch

    // gx ring: [buf][step][gate-tile m][lane] f32x4 = 3*8*4*64*16 B = 96 KiB
    __shared__ f32x4 gxbuf[3][CS][4][64];
    __shared__ int prod_done[2];
    __shared__ int cons_done;

    if (threadIdx.x == 0) {
        prod_done[0] = 0; prod_done[1] = 0; cons_done = 0;
    }

    // ================= producer-side state =================
    half8 WihF[4][2];
    f32x4 biasC[4];
    float4 xr[4][4];                       // 4 staged steps per producer
    const int pofs = (wave - 1) * 4;       // this producer's step offset
    const float* xl = x + (size_t)b * (Tn * Fn) + lhi * 8;

    if (wave >= 1) {
#pragma unroll
        for (int m = 0; m < 4; ++m)
#pragma unroll
            for (int kh = 0; kh < 2; ++kh) {
                const float* wr = Wih + (m * 16 + l15) * Fn + kh * 32 + lhi * 8;
                float4 w0 = *reinterpret_cast<const float4*>(wr);
                float4 w1 = *reinterpret_cast<const float4*>(wr + 4);
                WihF[m][kh] = to_half8(w0, w1);
            }
#pragma unroll
        for (int m = 0; m < 4; ++m) {
            float4 v0 = *reinterpret_cast<const float4*>(bih + m * 16 + lhi * 4);
            float4 v1 = *reinterpret_cast<const float4*>(bhh + m * 16 + lhi * 4);
            biasC[m][0] = v0.x + v1.x; biasC[m][1] = v0.y + v1.y;
            biasC[m][2] = v0.z + v1.z; biasC[m][3] = v0.w + v1.w;
        }
        // prologue: stage my 4 steps of chunk 0
#pragma unroll
        for (int s = 0; s < 4; ++s) {
            const float* xp = xl + (pofs + s) * Fn;
            xr[s][0] = *reinterpret_cast<const float4*>(xp);
            xr[s][1] = *reinterpret_cast<const float4*>(xp + 4);
            xr[s][2] = *reinterpret_cast<const float4*>(xp + 32);
            xr[s][3] = *reinterpret_cast<const float4*>(xp + 36);
        }
    }

    // ================= consumer-side state =================
    half4 WhhF[4];
#pragma unroll
    for (int m = 0; m < 4; ++m) {
        float4 w = *reinterpret_cast<const float4*>(Whh + (m * 16 + l15) * Hn + lhi * 4);
        WhhF[m][0] = (_Float16)w.x; WhhF[m][1] = (_Float16)w.y;
        WhhF[m][2] = (_Float16)w.z; WhhF[m][3] = (_Float16)w.w;
    }

    f32x4 cst = { 0.0f, 0.0f, 0.0f, 0.0f };
    half4 hHi = { 0, 0, 0, 0 };
    float hcur[4] = { 0.0f, 0.0f, 0.0f, 0.0f };

    auto recur = [&](f32x4 (&g)[4]) {
        // f-gate first: it heads the serial spine (f -> c -> tanh -> h)
        f32x4 pre1 = __builtin_amdgcn_mfma_f32_16x16x16f16(WhhF[1], hHi, g[1], 0, 0, 0);
        f32x4 pre0 = __builtin_amdgcn_mfma_f32_16x16x16f16(WhhF[0], hHi, g[0], 0, 0, 0);
        f32x4 pre2 = __builtin_amdgcn_mfma_f32_16x16x16f16(WhhF[2], hHi, g[2], 0, 0, 0);
        f32x4 pre3 = __builtin_amdgcn_mfma_f32_16x16x16f16(WhhF[3], hHi, g[3], 0, 0, 0);
#pragma unroll
        for (int r = 0; r < 4; ++r) {
            float fg = sigm(pre1[r]);
            float ig = sigm(pre0[r]);
            float gg = tanhe(pre2[r]);
            float og = sigm(pre3[r]);
            cst[r]  = fmaf(fg, cst[r], ig * gg);
            hcur[r] = og * tanhe(cst[r]);
        }
        auto p01 = __builtin_amdgcn_cvt_pkrtz(hcur[0], hcur[1]);
        auto p23 = __builtin_amdgcn_cvt_pkrtz(hcur[2], hcur[3]);
        hHi[0] = (_Float16)p01[0]; hHi[1] = (_Float16)p01[1];
        hHi[2] = (_Float16)p23[0]; hHi[3] = (_Float16)p23[1];
    };

    __syncthreads();   // flags + consumer state visible before pipeline starts

    if (wave >= 1) {
        // ================= producer loop =================
        const int pg = wave - 1;
#pragma unroll 1
        for (int i = 0; i < NCH; ++i) {
            if (i >= 3) {
                // buffer i%3 is free once consumer finished chunk i-3
                while (__hip_atomic_load(&cons_done, __ATOMIC_ACQUIRE,
                                         __HIP_MEMORY_SCOPE_WORKGROUP) < i - 2)
                    __builtin_amdgcn_s_sleep(1);
            }
            const int bi  = i % 3;
            const int cnx = (i + 1 < NCH) ? i + 1 : NCH - 1;   // clamp
#pragma unroll
            for (int s = 0; s < 4; ++s) {
                half8 f0 = to_half8(xr[s][0], xr[s][1]);
                half8 f1 = to_half8(xr[s][2], xr[s][3]);
                const float* xp = xl + (size_t)(cnx * CS + pofs + s) * Fn;
                xr[s][0] = *reinterpret_cast<const float4*>(xp);
                xr[s][1] = *reinterpret_cast<const float4*>(xp + 4);
                xr[s][2] = *reinterpret_cast<const float4*>(xp + 32);
                xr[s][3] = *reinterpret_cast<const float4*>(xp + 36);
#pragma unroll
                for (int m = 0; m < 4; ++m) {
                    f32x4 acc = __builtin_amdgcn_mfma_f32_16x16x32_f16(
                        WihF[m][0], f0, biasC[m], 0, 0, 0);
                    acc = __builtin_amdgcn_mfma_f32_16x16x32_f16(
                        WihF[m][1], f1, acc, 0, 0, 0);
                    gxbuf[bi][pofs + s][m][lane] = acc;
                }
            }
            if (lane == 0)
                __hip_atomic_store(&prod_done[pg], i + 1, __ATOMIC_RELEASE,
                                   __HIP_MEMORY_SCOPE_WORKGROUP);
        }
    } else {
        // ================= consumer loop =================
#pragma unroll 1
        for (int j = 0; j < NCH; ++j) {
            while (__hip_atomic_load(&prod_done[0], __ATOMIC_ACQUIRE,
                                     __HIP_MEMORY_SCOPE_WORKGROUP) < j + 1 ||
                   __hip_atomic_load(&prod_done[1], __ATOMIC_ACQUIRE,
                                     __HIP_MEMORY_SCOPE_WORKGROUP) < j + 1)
                __builtin_amdgcn_s_sleep(1);
            const int bi = j % 3;
            f32x4 gA[4], gB[4];
#pragma unroll
            for (int m = 0; m < 4; ++m) gA[m] = gxbuf[bi][0][m][lane];
#pragma unroll
            for (int m = 0; m < 4; ++m) gB[m] = gxbuf[bi][1][m][lane];
            recur(gA);
#pragma unroll
            for (int m = 0; m < 4; ++m) gA[m] = gxbuf[bi][2][m][lane];
            recur(gB);
#pragma unroll
            for (int m = 0; m < 4; ++m) gB[m] = gxbuf[bi][3][m][lane];
            recur(gA);
#pragma unroll
            for (int m = 0; m < 4; ++m) gA[m] = gxbuf[bi][4][m][lane];
            recur(gB);
#pragma unroll
            for (int m = 0; m < 4; ++m) gB[m] = gxbuf[bi][5][m][lane];
            recur(gA);
#pragma unroll
            for (int m = 0; m < 4; ++m) gA[m] = gxbuf[bi][6][m][lane];
            recur(gB);
#pragma unroll
            for (int m = 0; m < 4; ++m) gB[m] = gxbuf[bi][7][m][lane];
            recur(gA);
            recur(gB);
            if (lane == 0)
                __hip_atomic_store(&cons_done, j + 1, __ATOMIC_RELEASE,
                                   __HIP_MEMORY_SCOPE_WORKGROUP);
        }

        // ============ epilogue: Linear(16->1) + sigmoid ============
        float4 wo = *reinterpret_cast<const float4*>(Wout + lhi * 4);
        float po = hcur[0] * wo.x;
        po = fmaf(hcur[1], wo.y, po);
        po = fmaf(hcur[2], wo.z, po);
        po = fmaf(hcur[3], wo.w, po);
        po += __shfl_xor(po, 16);
        po += __shfl_xor(po, 32);
        if (lhi == 0)
            out[b] = sigm(po + bout[0]);
    }
}

extern "C" void kernel_launch(void* const* d_in, const int* in_sizes, int n_in,
                              void* d_out, int out_size, void* d_ws, size_t ws_size,
                              hipStream_t stream) {
    const float* x    = (const float*)d_in[0];
    const float* Wih  = (const float*)d_in[1];
    const float* Whh  = (const float*)d_in[2];
    const float* bih  = (const float*)d_in[3];
    const float* bhh  = (const float*)d_in[4];
    const float* Wout = (const float*)d_in[5];
    const float* bout = (const float*)d_in[6];
    float* out = (float*)d_out;

    lstm_fused<<<dim3(Bsz / 16), dim3(192), 0, stream>>>(
        x, Wih, Whh, bih, bhh, Wout, bout, out);
}

// Round 15
// 66.197 us; speedup vs baseline: 1.4836x; 1.1177x over previous
//
#include <hip/hip_runtime.h>

// Fused LSTM: B=4096, T=200, F=64, H=16, O=1.
// R9 structure (best: 72.7us) + TRANS-COUNT surgery (issue-bound consumer,
// trans ~16cy/instr wave64):
//  - activation scales (-log2e for i/f/o, -2log2e for g) folded into
//    Wih/Whh/bias (R11 proved folding innocent; R10/R11 failed on bout).
//  - product forms: sigma(i)*tanh(g) = (1-eg)/((1+ei)(1+eg)),
//                   sigma(o)*tanh(c) = (1-ec)/((1+eo)(1+ec))
//  - paired reciprocals: {1/a,1/b} from one rcp(a*b) + 3 muls.
//  Trans per step: 40 -> 20 exp2 + 6 rcp = 26.
// Everything else identical to R9: producer/consumer, 3 waves/block
// (1 consumer + 2 producers), 16 batches/block, gx via MFMA into 3-deep
// LDS ring, lgkmcnt-only chunk barriers, 1-MFMA f16 recurrence.

#define Bsz 4096
#define Tn  200
#define Fn  64
#define Hn  16
#define CS  8     // steps per chunk
#define NCH 25    // chunks (25*8 = 200)

#define CM1 -1.4426950408889634f   // -log2(e)
#define CM2 -2.8853900817779268f   // -2*log2(e)

typedef _Float16 half8 __attribute__((ext_vector_type(8)));
typedef _Float16 half4 __attribute__((ext_vector_type(4)));
typedef float    f32x4 __attribute__((ext_vector_type(4)));

__device__ __forceinline__ half8 to_half8s(const float4& a, const float4& b, float s) {
    half8 h;
    h[0] = (_Float16)(a.x * s); h[1] = (_Float16)(a.y * s);
    h[2] = (_Float16)(a.z * s); h[3] = (_Float16)(a.w * s);
    h[4] = (_Float16)(b.x * s); h[5] = (_Float16)(b.y * s);
    h[6] = (_Float16)(b.z * s); h[7] = (_Float16)(b.w * s);
    return h;
}

__device__ __forceinline__ float sigm(float z) {
    return __builtin_amdgcn_rcpf(1.0f + __builtin_amdgcn_exp2f(z * CM1));
}

// {1/a, 1/b} from a single rcp
__device__ __forceinline__ void pair_rcp(float a, float b, float& ra, float& rb) {
    float rp = __builtin_amdgcn_rcpf(a * b);
    ra = rp * b;
    rb = rp * a;
}

// LDS-visibility-only barrier: does NOT drain vmcnt (register-targeted
// global loads stay in flight across it).
__device__ __forceinline__ void lds_barrier() {
    __builtin_amdgcn_sched_barrier(0);
    asm volatile("s_waitcnt lgkmcnt(0)" ::: "memory");
    __builtin_amdgcn_s_barrier();
    __builtin_amdgcn_sched_barrier(0);
}

__global__ __launch_bounds__(192, 1) void lstm_fused(
    const float* __restrict__ x,     // [B, T, F]
    const float* __restrict__ Wih,   // [64, 64]
    const float* __restrict__ Whh,   // [64, 16]
    const float* __restrict__ bih,   // [64]
    const float* __restrict__ bhh,   // [64]
    const float* __restrict__ Wout,  // [1, 16]
    const float* __restrict__ bout,  // [1]
    float* __restrict__ out)         // [B, 1]
{
    const int lane = threadIdx.x & 63;
    const int wave = threadIdx.x >> 6;   // 0 = consumer, 1/2 = producers
    const int l15  = lane & 15;
    const int lhi  = lane >> 4;
    const int b    = (int)blockIdx.x * 16 + l15;   // per-lane batch

    // gx ring: [buf][step][gate-tile m][lane] f32x4 = 3*8*4*64*16 B = 96 KiB
    __shared__ f32x4 gxbuf[3][CS][4][64];

    // gate scale per tile m (0=i,1=f,2=g,3=o)
    const float scm[4] = { CM1, CM1, CM2, CM1 };

    // ================= producer-side state =================
    half8 WihF[4][2];
    f32x4 biasC[4];
    float4 xr[4][4];                       // 4 staged steps per producer
    const int pofs = (wave - 1) * 4;       // this producer's step offset
    const float* xl = x + (size_t)b * (Tn * Fn) + lhi * 8;

    if (wave >= 1) {
#pragma unroll
        for (int m = 0; m < 4; ++m) {
            const float s = scm[m];
#pragma unroll
            for (int kh = 0; kh < 2; ++kh) {
                const float* wr = Wih + (m * 16 + l15) * Fn + kh * 32 + lhi * 8;
                float4 w0 = *reinterpret_cast<const float4*>(wr);
                float4 w1 = *reinterpret_cast<const float4*>(wr + 4);
                WihF[m][kh] = to_half8s(w0, w1, s);
            }
            float4 v0 = *reinterpret_cast<const float4*>(bih + m * 16 + lhi * 4);
            float4 v1 = *reinterpret_cast<const float4*>(bhh + m * 16 + lhi * 4);
            biasC[m][0] = (v0.x + v1.x) * s; biasC[m][1] = (v0.y + v1.y) * s;
            biasC[m][2] = (v0.z + v1.z) * s; biasC[m][3] = (v0.w + v1.w) * s;
        }
        // prologue: stage my 4 steps of chunk 0
#pragma unroll
        for (int s = 0; s < 4; ++s) {
            const float* xp = xl + (pofs + s) * Fn;
            xr[s][0] = *reinterpret_cast<const float4*>(xp);
            xr[s][1] = *reinterpret_cast<const float4*>(xp + 4);
            xr[s][2] = *reinterpret_cast<const float4*>(xp + 32);
            xr[s][3] = *reinterpret_cast<const float4*>(xp + 36);
        }
    }

    // ================= consumer-side state =================
    half4 WhhF[4];   // Whh rows scaled by gate scale
#pragma unroll
    for (int m = 0; m < 4; ++m) {
        const float s = scm[m];
        float4 w = *reinterpret_cast<const float4*>(Whh + (m * 16 + l15) * Hn + lhi * 4);
        WhhF[m][0] = (_Float16)(w.x * s); WhhF[m][1] = (_Float16)(w.y * s);
        WhhF[m][2] = (_Float16)(w.z * s); WhhF[m][3] = (_Float16)(w.w * s);
    }

    f32x4 cst = { 0.0f, 0.0f, 0.0f, 0.0f };
    half4 hHi = { 0, 0, 0, 0 };
    float hcur[4] = { 0.0f, 0.0f, 0.0f, 0.0f };

    // one recurrence + cell step; pre values arrive PRE-SCALED:
    //   pre_i/f/o = -log2e * z,  pre_g = -2log2e * z
    auto recur = [&](f32x4 (&g)[4]) {
        f32x4 pf = __builtin_amdgcn_mfma_f32_16x16x16f16(WhhF[1], hHi, g[1], 0, 0, 0);
        f32x4 pi = __builtin_amdgcn_mfma_f32_16x16x16f16(WhhF[0], hHi, g[0], 0, 0, 0);
        f32x4 pg = __builtin_amdgcn_mfma_f32_16x16x16f16(WhhF[2], hHi, g[2], 0, 0, 0);
        f32x4 po = __builtin_amdgcn_mfma_f32_16x16x16f16(WhhF[3], hHi, g[3], 0, 0, 0);

        float df[4], dig[4], eg[4], eo[4];
#pragma unroll
        for (int r = 0; r < 4; ++r) {
            float ef = __builtin_amdgcn_exp2f(pf[r]);      // e^-f
            float ei = __builtin_amdgcn_exp2f(pi[r]);      // e^-i
            eg[r]    = __builtin_amdgcn_exp2f(pg[r]);      // e^-2g
            eo[r]    = __builtin_amdgcn_exp2f(po[r]);      // e^-o
            df[r]  = 1.0f + ef;
            dig[r] = (1.0f + ei) * (1.0f + eg[r]);
        }
        // paired reciprocals: forget gates and ig-denominators
        float rf[4], rig[4];
        pair_rcp(df[0],  df[1],  rf[0],  rf[1]);
        pair_rcp(df[2],  df[3],  rf[2],  rf[3]);
        pair_rcp(dig[0], dig[1], rig[0], rig[1]);
        pair_rcp(dig[2], dig[3], rig[2], rig[3]);

        float ec[4], dh[4];
#pragma unroll
        for (int r = 0; r < 4; ++r) {
            // c' = sigma(f)*c + sigma(i)*tanh(g) = rf*c + (1-eg)*rig
            cst[r] = fmaf(rf[r], cst[r], (1.0f - eg[r]) * rig[r]);
            ec[r]  = __builtin_amdgcn_exp2f(cst[r] * CM2);   // e^-2c
            dh[r]  = (1.0f + eo[r]) * (1.0f + ec[r]);
        }
        float rh[4];
        pair_rcp(dh[0], dh[1], rh[0], rh[1]);
        pair_rcp(dh[2], dh[3], rh[2], rh[3]);
#pragma unroll
        for (int r = 0; r < 4; ++r)
            hcur[r] = (1.0f - ec[r]) * rh[r];   // sigma(o)*tanh(c)

        auto p01 = __builtin_amdgcn_cvt_pkrtz(hcur[0], hcur[1]);
        auto p23 = __builtin_amdgcn_cvt_pkrtz(hcur[2], hcur[3]);
        hHi[0] = (_Float16)p01[0]; hHi[1] = (_Float16)p01[1];
        hHi[2] = (_Float16)p23[0]; hHi[3] = (_Float16)p23[1];
    };

    // ================= pipelined main loop =================
#pragma unroll 1
    for (int i = 0; i < NCH + 2; ++i) {
        lds_barrier();
        if (wave >= 1) {
            // ---- producers: compute my 4 steps of chunk i; reload xr[s]
            //      (chunk i+1) right after consuming it
            if (i < NCH) {
                const int bi  = i % 3;
                const int cnx = (i + 1 < NCH) ? i + 1 : NCH - 1;   // clamp
#pragma unroll
                for (int s = 0; s < 4; ++s) {
                    half8 f0 = to_half8s(xr[s][0], xr[s][1], 1.0f);
                    half8 f1 = to_half8s(xr[s][2], xr[s][3], 1.0f);
                    const float* xp = xl + (size_t)(cnx * CS + pofs + s) * Fn;
                    xr[s][0] = *reinterpret_cast<const float4*>(xp);
                    xr[s][1] = *reinterpret_cast<const float4*>(xp + 4);
                    xr[s][2] = *reinterpret_cast<const float4*>(xp + 32);
                    xr[s][3] = *reinterpret_cast<const float4*>(xp + 36);
#pragma unroll
                    for (int m = 0; m < 4; ++m) {
                        f32x4 acc = __builtin_amdgcn_mfma_f32_16x16x32_f16(
                            WihF[m][0], f0, biasC[m], 0, 0, 0);
                        acc = __builtin_amdgcn_mfma_f32_16x16x32_f16(
                            WihF[m][1], f1, acc, 0, 0, 0);
                        gxbuf[bi][pofs + s][m][lane] = acc;
                    }
                }
            }
        } else {
            // ---- consumer: recurrence over chunk i-2
            if (i >= 2) {
                const int bi = (i - 2) % 3;
                f32x4 gA[4], gB[4];
#pragma unroll
                for (int m = 0; m < 4; ++m) gA[m] = gxbuf[bi][0][m][lane];
#pragma unroll
                for (int m = 0; m < 4; ++m) gB[m] = gxbuf[bi][1][m][lane];
                recur(gA);
#pragma unroll
                for (int m = 0; m < 4; ++m) gA[m] = gxbuf[bi][2][m][lane];
                recur(gB);
#pragma unroll
                for (int m = 0; m < 4; ++m) gB[m] = gxbuf[bi][3][m][lane];
                recur(gA);
#pragma unroll
                for (int m = 0; m < 4; ++m) gA[m] = gxbuf[bi][4][m][lane];
                recur(gB);
#pragma unroll
                for (int m = 0; m < 4; ++m) gB[m] = gxbuf[bi][5][m][lane];
                recur(gA);
#pragma unroll
                for (int m = 0; m < 4; ++m) gA[m] = gxbuf[bi][6][m][lane];
                recur(gB);
#pragma unroll
                for (int m = 0; m < 4; ++m) gB[m] = gxbuf[bi][7][m][lane];
                recur(gA);
                recur(gB);
            }
        }
    }

    // ================= epilogue: Linear(16->1) + sigmoid =================
    if (wave == 0) {
        float4 wo = *reinterpret_cast<const float4*>(Wout + lhi * 4);
        float po = hcur[0] * wo.x;
        po = fmaf(hcur[1], wo.y, po);
        po = fmaf(hcur[2], wo.z, po);
        po = fmaf(hcur[3], wo.w, po);
        po += __shfl_xor(po, 16);
        po += __shfl_xor(po, 32);
        if (lhi == 0)
            out[b] = sigm(po + bout[0]);
    }
}

extern "C" void kernel_launch(void* const* d_in, const int* in_sizes, int n_in,
                              void* d_out, int out_size, void* d_ws, size_t ws_size,
                              hipStream_t stream) {
    const float* x    = (const float*)d_in[0];
    const float* Wih  = (const float*)d_in[1];
    const float* Whh  = (const float*)d_in[2];
    const float* bih  = (const float*)d_in[3];
    const float* bhh  = (const float*)d_in[4];
    const float* Wout = (const float*)d_in[5];
    const float* bout = (const float*)d_in[6];
    float* out = (float*)d_out;

    lstm_fused<<<dim3(Bsz / 16), dim3(192), 0, stream>>>(
        x, Wih, Whh, bih, bhh, Wout, bout, out);
}